// Round 13
// baseline (82.034 us; speedup 1.0000x reference)
//
#include <hip/hip_runtime.h>
#include <hip/hip_bf16.h>
#include <hip/hip_fp16.h>
#include <stdint.h>

typedef __attribute__((ext_vector_type(8))) _Float16 f16x8;
typedef __attribute__((ext_vector_type(2))) __fp16 hf16x2;
typedef __attribute__((ext_vector_type(4))) float f32x4;

#define B_  32
#define S_  512
#define K_  512
#define H_  1024
#define HS  64           // h-cols per block
#define SC  128          // s-rows per chunk
#define NKT 8            // K_/64
#define NSC 4            // S_/SC

// LDS: x dbuf 2x16K | W dbuf 2x24K = 80KB -> 2 blocks/CU. No zf plane, no
// handoff: scan is fully wave-local (gate-major wave mapping).
#define XD0 0
#define XD1 16384
#define WD0 32768
#define WD1 57344
#define LDS_BYTES 81920

#define GLDS(src, dst) __builtin_amdgcn_global_load_lds( \
    (const __attribute__((address_space(1))) void*)(src), \
    (__attribute__((address_space(3))) void*)(dst), 16, 0, 0)

__device__ inline float sigm(float v) {
    return __builtin_amdgcn_rcpf(1.f + __expf(-v));
}

__device__ inline float unpk(uint32_t u, int hi) {
    union { uint32_t u; _Float16 h[2]; } x; x.u = u;
    return (float)x.h[hi];
}
__device__ inline uint32_t pkrtz(float a, float b) {
    union { hf16x2 v; uint32_t u; } x;
    x.v = __builtin_amdgcn_cvt_pkrtz(a, b);
    return x.u;
}

// ---------------------------------------------------------------------------
// f32 -> f16 conversion for x and W. 8 elems/thread, 16B stores.
// ---------------------------------------------------------------------------
struct alignas(16) H8 { _Float16 h[8]; };

__global__ __launch_bounds__(256) void cvt_xw(
    const float* __restrict__ x, _Float16* __restrict__ xh, int n8x,
    const float* __restrict__ W, _Float16* __restrict__ Wh, int n8w)
{
    const int t = blockIdx.x * 256 + threadIdx.x;
    const float* src; _Float16* dst; int i;
    if (t < n8x)             { src = x; dst = xh; i = t; }
    else if (t < n8x + n8w)  { src = W; dst = Wh; i = t - n8x; }
    else return;
    const float4* p = (const float4*)(src + (size_t)i * 8);
    const float4 a = p[0], b = p[1];
    H8 o;
    o.h[0] = (_Float16)a.x; o.h[1] = (_Float16)a.y;
    o.h[2] = (_Float16)a.z; o.h[3] = (_Float16)a.w;
    o.h[4] = (_Float16)b.x; o.h[5] = (_Float16)b.y;
    o.h[6] = (_Float16)b.z; o.h[7] = (_Float16)b.w;
    ((H8*)dst)[i] = o;
}

// ---------------------------------------------------------------------------
// Fused GEMM + activations + in-register affine scan, software-pipelined
// across chunks.
// Grid 512 = (b, hs) XCD-affine. Block 256 = 4 GATE-MAJOR waves: wave w owns
// h-strip w*16..w*16+15 with ALL 3 gates and ALL 128 s -> acc[8][3]; one
// h-col per lane (hcol = hs*64 + w*16 + fr). Scan never crosses waves.
// Chunk pipeline: at chunk end, raw y's pack to f16 pairs (pk, 48 VGPR);
// during the NEXT chunk's K-loop, kt's tail runs slice m=kt of the previous
// chunk's epilogue (unpack -> activations -> run-compose -> fq-Kogge-Stone
// -> backfill -> 4 out stores). GATE = counted vmcnt(4): 4 newer slice
// stores fly, 10 older stage glds FIFO-complete. Last chunk flushes after
// the loop.
// ---------------------------------------------------------------------------
__global__ __launch_bounds__(256, 2) void qrnn_fused(
    const _Float16* __restrict__ xh,   // [B*S, K]
    const _Float16* __restrict__ Wh,   // [3H, K]
    const float* __restrict__ bias,    // [3H]
    const float* __restrict__ c0,      // [B, H]
    float* __restrict__ out)           // [B,S,H] ++ [B,H]
{
    extern __shared__ char smem[];

    const int tid  = threadIdx.x;
    const int lane = tid & 63;
    const int wid  = tid >> 6;         // h-strip (16 h)
    const int fq   = lane >> 4;
    const int fr   = lane & 15;

    const int bid = blockIdx.x;
    const int b   = (bid & 7) + ((bid >> 7) << 3);
    const int hs  = (bid >> 3) & 15;

    const int hcol = hs * HS + wid * 16 + fr;
    const float bz  = bias[hcol];
    const float bff = bias[H_ + hcol];
    const float bo  = bias[2 * H_ + hcol];
    float cc = c0[b * H_ + hcol];
    float FP = 1.f, GP = 0.f;

    const int srow  = lane >> 3;
    const int scolb = (((lane & 7) ^ (lane >> 3)) << 4);
    const _Float16* xbase = xh + (size_t)(b * S_) * K_;

    // half-stage: ks=0 issues chunk-ids i=0..4, ks=1 issues i=5..9
    auto STAGEH = [&](int sc_, int kt_, int xoff, int woff, int half) {
        #pragma unroll
        for (int i = half * 5; i < half * 5 + 5; ++i) {
            const int cid = wid * 10 + i;          // 0..39 chunks of 1KB
            if (cid < 16) {                        // x tile rows (s')
                const int r = cid * 8 + srow;
                const char* src = (const char*)(xbase + (size_t)(sc_ * SC + r) * K_ + kt_ * 64) + scolb;
                GLDS(src, smem + xoff + cid * 1024);
            } else {                               // W tile rows (0..191)
                const int r = (cid - 16) * 8 + srow;
                const int wrow = (r >> 6) * H_ + hs * HS + (r & 63);
                const char* src = (const char*)(Wh + (size_t)wrow * K_ + kt_ * 64) + scolb;
                GLDS(src, smem + woff + (cid - 16) * 1024);
            }
        }
    };

    f32x4 acc[8][3] = {};
    uint32_t pk[8][6];                 // prev-chunk raw y: [m][0..1]=z,[2..3]=f,[4..5]=o

    // one m-slice of the previous chunk's epilogue + backfill
    auto SLICE = [&](int m, int scp) {
        if (m == 0) { FP = 1.f; GP = 0.f; }
        float fj[4], gj[4], oj[4];
        float Fr = 1.f, Gr = 0.f;
        #pragma unroll
        for (int j = 0; j < 4; ++j) {
            const float zy = unpk(pk[m][j >> 1], j & 1);
            const float fy = unpk(pk[m][2 + (j >> 1)], j & 1);
            const float oy = unpk(pk[m][4 + (j >> 1)], j & 1);
            const float z = 2.f * sigm(2.f * (zy + bz)) - 1.f;  // tanh
            const float f = sigm(fy + bff);
            const float g = (1.f - f) * z;
            fj[j] = f; gj[j] = g; oj[j] = sigm(oy + bo);
            Gr = __builtin_fmaf(f, Gr, g);
            Fr = f * Fr;
        }
        // Kogge-Stone over fq (4 groups of 16 lanes)
        float F1 = __shfl(Fr, lane - 16), G1 = __shfl(Gr, lane - 16);
        if (fq >= 1) { Gr = __builtin_fmaf(Fr, G1, Gr); Fr = Fr * F1; }
        float F2 = __shfl(Fr, lane - 32), G2 = __shfl(Gr, lane - 32);
        if (fq >= 2) { Gr = __builtin_fmaf(Fr, G2, Gr); Fr = Fr * F2; }
        float FE = __shfl(Fr, lane - 16), GE = __shfl(Gr, lane - 16);
        if (fq == 0) { FE = 1.f; GE = 0.f; }
        const float FM = __shfl(Fr, 48 + fr);     // full 16-step map of m
        const float GM = __shfl(Gr, 48 + fr);
        const float FsSm = FE * FP;
        const float GsSm = __builtin_fmaf(FE, GP, GE);
        GP = __builtin_fmaf(FM, GP, GM);
        FP = FM * FP;
        // backfill + stores (cin = cc, the chunk-entry state)
        float cr = __builtin_fmaf(FsSm, cc, GsSm);
        float* orow = out + (size_t)(b * S_ + scp * SC + m * 16 + fq * 4) * H_ + hcol;
        #pragma unroll
        for (int j = 0; j < 4; ++j) {
            cr = __builtin_fmaf(fj[j], cr, gj[j]);
            orow[(size_t)j * H_] = oj[j] * cr;
        }
        if (m == 7) cc = __builtin_fmaf(FP, cc, GP);
    };

    STAGEH(0, 0, XD0, WD0, 0);
    STAGEH(0, 0, XD0, WD0, 1);

    for (int sc = 0; sc < NSC; ++sc) {
        #pragma unroll
        for (int kt = 0; kt < NKT; ++kt) {
            const int cur  = kt & 1;
            const int curx = cur ? XD1 : XD0;
            const int curw = cur ? WD1 : WD0;
            const int nxtx = cur ? XD0 : XD1;
            const int nxtw = cur ? WD0 : WD1;

            // --- GATE: counted wait; stage(kt) landed on all waves ---------
            if (sc == 0) asm volatile("s_waitcnt vmcnt(0)" ::: "memory");
            else         asm volatile("s_waitcnt vmcnt(4)" ::: "memory");
            __builtin_amdgcn_s_barrier();
            __builtin_amdgcn_sched_barrier(0);

            #pragma unroll
            for (int ks = 0; ks < 2; ++ks) {
                f16x8 af[8], bf[3];
                #pragma unroll
                for (int m = 0; m < 8; ++m) {
                    const int row = m * 16 + fr;
                    const int kb  = ks * 64 + fq * 16;
                    af[m] = *(const f16x8*)(smem + curx + row * 128 + (kb ^ ((row & 7) << 4)));
                }
                #pragma unroll
                for (int n = 0; n < 3; ++n) {
                    const int row = n * 64 + wid * 16 + fr;
                    const int kb  = ks * 64 + fq * 16;
                    bf[n] = *(const f16x8*)(smem + curw + row * 128 + (kb ^ ((row & 7) << 4)));
                }

                if (kt + 1 < NKT)      STAGEH(sc, kt + 1, nxtx, nxtw, ks);
                else if (sc + 1 < NSC) STAGEH(sc + 1, 0, nxtx, nxtw, ks);

                __builtin_amdgcn_s_barrier();
                asm volatile("s_waitcnt lgkmcnt(0)" ::: "memory");
                __builtin_amdgcn_sched_barrier(0);
                __builtin_amdgcn_s_setprio(1);
                #pragma unroll
                for (int m = 0; m < 8; ++m)
                    #pragma unroll
                    for (int n = 0; n < 3; ++n)
                        acc[m][n] = __builtin_amdgcn_mfma_f32_16x16x32_f16(
                            af[m], bf[n], acc[m][n], 0, 0, 0);
                __builtin_amdgcn_s_setprio(0);
                if (ks == 0) __builtin_amdgcn_s_barrier();
            }

            // --- spliced epilogue slice of the previous chunk --------------
            if (sc > 0) SLICE(kt, sc - 1);
        }

        // --- pack raw y's, reset acc for next chunk -------------------------
        #pragma unroll
        for (int m = 0; m < 8; ++m)
            #pragma unroll
            for (int n = 0; n < 3; ++n) {
                pk[m][n * 2 + 0] = pkrtz(acc[m][n][0], acc[m][n][1]);
                pk[m][n * 2 + 1] = pkrtz(acc[m][n][2], acc[m][n][3]);
                acc[m][n] = (f32x4){0.f, 0.f, 0.f, 0.f};
            }
    }

    // --- flush: chunk 3's epilogue standalone -------------------------------
    #pragma unroll
    for (int m = 0; m < 8; ++m) SLICE(m, NSC - 1);

    // c_last tail: [1,B,H] appended after [B,S,H]
    if (fq == 0) out[(size_t)B_ * S_ * H_ + b * H_ + hcol] = cc;
}

extern "C" void kernel_launch(void* const* d_in, const int* in_sizes, int n_in,
                              void* d_out, int out_size, void* d_ws, size_t ws_size,
                              hipStream_t stream) {
    const float* x = (const float*)d_in[0];
    const float* h = (const float*)d_in[1];
    const float* W = (const float*)d_in[2];
    const float* b = (const float*)d_in[3];
    float* out = (float*)d_out;

    _Float16* xh = (_Float16*)d_ws;
    _Float16* Wh = xh + (size_t)B_ * S_ * K_;

    (void)hipFuncSetAttribute((const void*)qrnn_fused,
                              hipFuncAttributeMaxDynamicSharedMemorySize, LDS_BYTES);

    const int n8x = B_ * S_ * K_ / 8;   // 1048576
    const int n8w = 3 * H_ * K_ / 8;    // 196608
    cvt_xw<<<(n8x + n8w + 255) / 256, 256, 0, stream>>>(x, xh, n8x, W, Wh, n8w);

    qrnn_fused<<<B_ * (H_ / HS), 256, LDS_BYTES, stream>>>(xh, Wh, b, h, out);
}